// Round 5
// baseline (1231.337 us; speedup 1.0000x reference)
//
#include <hip/hip_runtime.h>
#include <hip/hip_bf16.h>

#define N 224
#define TS 32
// LDS tiles are stored UNPADDED (pitch 32). All LDS access is ds_read/write_b128
// at 4-float-aligned columns: each wave instruction lands 8 lanes per 4-bank
// group = the 1024B/instr service minimum -> no conflict penalty, and
// 8*32*32*4 = 32768 B -> exactly 5 blocks/CU (163840 B LDS).

// Group element g maps output pixel (i,j) -> source pixel m_g(i,j):
//   m0:(i,j) m1:(j,ri) m2:(ri,rj) m3:(rj,i) m4:(i,rj) m5:(j,i) m6:(ri,j) m7:(rj,ri)
// COMP[g][h] = index of m_g∘m_h; slot tables packed 3 bits per h (octal digit h).
// PACKG: generic orbit slots = COMP[g][h] (verified rounds 1-4).
constexpr unsigned PACKG[8] = {076543210u,065470321u,054761032u,047652103u,
                               032107654u,021034765u,010325476u,003216547u};
// PACK1: axis orbit (J==3), slot = CAN1[COMP[g][h]], CAN1={0,1,2,3,0,3,2,1}, h<4
constexpr unsigned PACK1[8] = {03210u,00321u,01032u,02103u,01230u,00123u,03012u,02301u};
// PACK2: diagonal orbit (I==J), CAN2={0,1,2,3,1,0,3,2}, h<4
constexpr unsigned PACK2[8] = {03210u,00321u,01032u,02103u,02301u,01230u,00123u,03012u};

// Accumulate group G's contribution to a 4x4 output micro-block.
// Source block rows are read as 4x ds_read_b128; transposed/reversed element
// selection is compile-time register indexing.
template<int G>
__device__ __forceinline__ void accum_group(float (&acc)[4][4], float coefg,
        const float* __restrict__ lds, int slot, int rbase, int cbase)
{
    float s[4][4];
    #pragma unroll
    for (int r = 0; r < 4; ++r) {
        const float4 v = *reinterpret_cast<const float4*>(
            &lds[slot * (TS * TS) + (rbase + r) * TS + cbase]);
        s[r][0] = v.x; s[r][1] = v.y; s[r][2] = v.z; s[r][3] = v.w;
    }
    #pragma unroll
    for (int a = 0; a < 4; ++a) {
        #pragma unroll
        for (int b = 0; b < 4; ++b) {
            const int r  = (G==0)?a : (G==1)?b : (G==2)?3-a : (G==3)?3-b
                         : (G==4)?a : (G==5)?b : (G==6)?3-a : 3-b;
            const int cc = (G==0)?b : (G==1)?3-a : (G==2)?3-b : (G==3)?a
                         : (G==4)?3-b : (G==5)?a : (G==6)?b : 3-a;
            acc[a][b] += coefg * s[r][cc];
        }
    }
}

__device__ __forceinline__ int tile_i(int h, int I, int J, int rI, int rJ) {
    const int h3 = h & 3;
    return (h3==0) ? I : (h3==1) ? J : (h3==2) ? rI : rJ;
}
__device__ __forceinline__ int tile_j(int h, int I, int J, int rI, int rJ) {
    const int h3 = h & 3;
    if (h < 4) return (h3==0) ? J : (h3==1) ? rI : (h3==2) ? rJ : I;
    return (h3==0) ? rJ : (h3==1) ? I : (h3==2) ? J : rI;
}

__global__ __launch_bounds__(256, 5) void popmi_kernel(
        const float* __restrict__ x, const float* __restrict__ theta,
        float* __restrict__ out)
{
    __shared__ float lds[8 * TS * TS];   // 32768 B

    // coefficients from theta (8 floats), recomputed per thread:
    // coef[g] = (BETA/w_sum)*softmax(theta)[g]; coef[0] += 1-BETA
    float th[8];
    #pragma unroll
    for (int i = 0; i < 8; ++i) th[i] = theta[i];
    float m = th[0];
    #pragma unroll
    for (int i = 1; i < 8; ++i) m = fmaxf(m, th[i]);
    float e[8], S = 0.f;
    #pragma unroll
    for (int i = 0; i < 8; ++i) { e[i] = expf(th[i] - m); S += e[i]; }
    float ws = 0.f;
    #pragma unroll
    for (int i = 0; i < 8; ++i) ws += e[i] / S;
    const float s0 = 0.5f / fmaxf(ws, 1e-12f);
    float c[8];
    #pragma unroll
    for (int i = 0; i < 8; ++i) c[i] = s0 * (e[i] / S);
    c[0] += 0.5f;

    const int bid = blockIdx.x;
    const int p   = bid / 10;           // plane
    const int o   = bid - p * 10;       // orbit id 0..9

    // orbit rep (I,J): OI={0,0,1,0,1,2,0,1,2,3} OJ={1,2,2,3,3,3,0,1,2,3}
    const int I  = (0x1A211040u >> (3 * o)) & 7;
    const int J  = (0x1A21B691u >> (3 * o)) & 7;
    const int rI = 6 - I, rJ = 6 - J;

    const float* plane  = x   + (size_t)p * (N * N);
    float*       oplane = out + (size_t)p * (N * N);

    const int tid = threadIdx.x;

    // ---- stage unique orbit tiles into LDS (float4, row-contiguous) ----
    const int srow = tid >> 3;          // 0..31
    const int scg  = (tid & 7) << 2;    // 0,4,...,28
    const int nu   = (o < 3) ? 8 : (o < 9) ? 4 : 1;
    for (int u = 0; u < nu; ++u) {      // block-uniform bound
        const int TIu = tile_i(u, I, J, rI, rJ);
        const int TJu = tile_j(u, I, J, rI, rJ);
        const float4 v = *reinterpret_cast<const float4*>(
            plane + (size_t)(TIu * TS + srow) * N + TJu * TS + scg);
        float* dst = &lds[u * (TS * TS) + srow * TS + scg];
        dst[0] = v.x; dst[1] = v.y; dst[2] = v.z; dst[3] = v.w;
    }
    __syncthreads();

    // ---- compute: each thread owns a 4x4 micro-block; wave w handles
    //      output tiles h = w (+4). All LDS reads are b128. ----
    const int w    = tid >> 6;
    const int lane = tid & 63;
    const int brow = lane >> 3;         // 0..7
    const int bcol = lane & 7;          // 0..7

    // row/col block bases (float index in tile): selected per-G at compile time
    const int r4[4] = {4 * brow, 4 * bcol, 28 - 4 * brow, 28 - 4 * bcol};
    const int c4[4] = {4 * bcol, 28 - 4 * brow, 28 - 4 * bcol, 4 * brow};

    unsigned pk[8];
    #pragma unroll
    for (int g = 0; g < 8; ++g)
        pk[g] = (o < 3) ? PACKG[g] : (o < 6) ? PACK1[g] : (o < 9) ? PACK2[g] : 0u;

    const int nIter = (o < 3) ? 2 : (o < 9) ? 1 : ((w == 0) ? 1 : 0);

    for (int it = 0; it < nIter; ++it) {
        const int h = w + 4 * it;
        float acc[4][4] = {{0.f,0.f,0.f,0.f},{0.f,0.f,0.f,0.f},
                           {0.f,0.f,0.f,0.f},{0.f,0.f,0.f,0.f}};

        accum_group<0>(acc, c[0], lds, (pk[0] >> (3*h)) & 7, r4[0], c4[0]);
        accum_group<1>(acc, c[1], lds, (pk[1] >> (3*h)) & 7, r4[1], c4[1]);
        accum_group<2>(acc, c[2], lds, (pk[2] >> (3*h)) & 7, r4[2], c4[2]);
        accum_group<3>(acc, c[3], lds, (pk[3] >> (3*h)) & 7, r4[3], c4[3]);
        accum_group<4>(acc, c[4], lds, (pk[4] >> (3*h)) & 7, r4[0], c4[2]);
        accum_group<5>(acc, c[5], lds, (pk[5] >> (3*h)) & 7, r4[1], c4[3]);
        accum_group<6>(acc, c[6], lds, (pk[6] >> (3*h)) & 7, r4[2], c4[0]);
        accum_group<7>(acc, c[7], lds, (pk[7] >> (3*h)) & 7, r4[3], c4[1]);

        const int TIh = tile_i(h, I, J, rI, rJ);
        const int TJh = tile_j(h, I, J, rI, rJ);
        float* obase = oplane + (size_t)(TIh * TS + 4 * brow) * N
                              + TJh * TS + 4 * bcol;
        #pragma unroll
        for (int r = 0; r < 4; ++r) {
            *reinterpret_cast<float4*>(obase + (size_t)r * N)
                = make_float4(acc[r][0], acc[r][1], acc[r][2], acc[r][3]);
        }
    }
}

extern "C" void kernel_launch(void* const* d_in, const int* in_sizes, int n_in,
                              void* d_out, int out_size, void* d_ws, size_t ws_size,
                              hipStream_t stream) {
    const float* x     = (const float*)d_in[0];
    const float* theta = (const float*)d_in[1];
    float* out = (float*)d_out;

    const int planes = in_sizes[0] / (N * N);   // 16*192 = 3072
    popmi_kernel<<<planes * 10, 256, 0, stream>>>(x, theta, out);
}

// Round 6
// 333.156 us; speedup vs baseline: 3.6960x; 3.6960x over previous
//
#include <hip/hip_runtime.h>
#include <hip/hip_bf16.h>

#define N 224
#define TS 32
#define NT 7
#define PITCH 33   // measured rounds 1-3: all access patterns <=2-way bank alias (free)

// Group element g maps output pixel (i,j) -> source pixel m_g(i,j):
//   m0:(i,j) m1:(j,ri) m2:(ri,rj) m3:(rj,i) m4:(i,rj) m5:(j,i) m6:(ri,j) m7:(rj,ri)
// COMP[g][h] = index of m_g∘m_h (verified rounds 1-5).
constexpr int COMP[8][8] = {
    {0,1,2,3,4,5,6,7},
    {1,2,3,0,7,4,5,6},
    {2,3,0,1,6,7,4,5},
    {3,0,1,2,5,6,7,4},
    {4,5,6,7,0,1,2,3},
    {5,6,7,4,3,0,1,2},
    {6,7,4,5,2,3,0,1},
    {7,4,5,6,1,2,3,0},
};
// canonical LDS slot (<4) for degenerate orbits
constexpr int CAN1[8] = {0,1,2,3,0,3,2,1};   // axis J==3
constexpr int CAN2[8] = {0,1,2,3,1,0,3,2};   // diagonal I==J

__device__ __forceinline__ int tile_i(int h, int I, int J, int rI, int rJ) {
    const int h3 = h & 3;
    return (h3==0) ? I : (h3==1) ? J : (h3==2) ? rI : rJ;
}
__device__ __forceinline__ int tile_j(int h, int I, int J, int rI, int rJ) {
    const int h3 = h & 3;
    if (h < 4) return (h3==0) ? J : (h3==1) ? rI : (h3==2) ? rJ : I;
    return (h3==0) ? rJ : (h3==1) ? I : (h3==2) ? J : rI;
}

__global__ __launch_bounds__(256, 4) void popmi_kernel(
        const float* __restrict__ x, const float* __restrict__ theta,
        float* __restrict__ out)
{
    __shared__ float lds[8][TS * PITCH];   // 33792 B -> 4 blocks/CU

    // coefficients from theta (8 floats), recomputed per thread:
    // coef[g] = (BETA/w_sum)*softmax(theta)[g]; coef[0] += 1-BETA
    float th[8];
    #pragma unroll
    for (int i = 0; i < 8; ++i) th[i] = theta[i];
    float m = th[0];
    #pragma unroll
    for (int i = 1; i < 8; ++i) m = fmaxf(m, th[i]);
    float e[8], S = 0.f;
    #pragma unroll
    for (int i = 0; i < 8; ++i) { e[i] = expf(th[i] - m); S += e[i]; }
    float ws = 0.f;
    #pragma unroll
    for (int i = 0; i < 8; ++i) ws += e[i] / S;
    const float s0 = 0.5f / fmaxf(ws, 1e-12f);
    float c[8];
    #pragma unroll
    for (int i = 0; i < 8; ++i) c[i] = s0 * (e[i] / S);
    c[0] += 0.5f;

    const int bid = blockIdx.x;
    const int p   = bid / 10;           // plane
    const int o   = bid - p * 10;       // orbit id 0..9

    // orbit rep (I,J): OI={0,0,1,0,1,2,0,1,2,3} OJ={1,2,2,3,3,3,0,1,2,3}
    const int I  = (0x1A211040u >> (3 * o)) & 7;
    const int J  = (0x1A21B691u >> (3 * o)) & 7;
    const int rI = 6 - I, rJ = 6 - J;

    const float* plane  = x   + (size_t)p * (N * N);
    float*       oplane = out + (size_t)p * (N * N);

    const int tid = threadIdx.x;
    const int ti  = tid >> 3;           // 0..31
    const int cg  = (tid & 7) << 2;     // 0,4,...,28
    const int rti = TS - 1 - ti;
    const int rcg = TS - 4 - cg;        // base col of the reversed quad

    // ---- stage unique orbit tiles into LDS (for the 4 transpose groups) ----
    const int nu = (o < 3) ? 8 : (o < 9) ? 4 : 1;
    for (int u = 0; u < nu; ++u) {      // block-uniform bound
        const int TIu = tile_i(u, I, J, rI, rJ);
        const int TJu = tile_j(u, I, J, rI, rJ);
        const float4 v = *reinterpret_cast<const float4*>(
            plane + (size_t)(TIu * TS + ti) * N + TJu * TS + cg);
        float* dst = &lds[u][ti * PITCH + cg];
        dst[0] = v.x; dst[1] = v.y; dst[2] = v.z; dst[3] = v.w;
    }
    __syncthreads();

    // row-contiguous global float4 from tile v at row rr, col base cb
    auto gload = [&](int v, int rr, int cb) -> float4 {
        return *reinterpret_cast<const float4*>(
            plane + (size_t)(tile_i(v,I,J,rI,rJ) * TS + rr) * N
                  + tile_j(v,I,J,rI,rJ) * TS + cb);
    };

    if (o < 3) {
        // ---------------- generic orbit: 8 output tiles ----------------
        #pragma unroll
        for (int h = 0; h < 8; ++h) {
            float a0 = 0.f, a1 = 0.f, a2 = 0.f, a3 = 0.f;
            // row-type groups straight from global (L1/L2-hot, coalesced)
            { const float4 r = gload(COMP[0][h], ti,  cg);   // g0: elem q
              a0 += c[0]*r.x; a1 += c[0]*r.y; a2 += c[0]*r.z; a3 += c[0]*r.w; }
            { const float4 r = gload(COMP[2][h], rti, rcg);  // g2: elem 3-q
              a0 += c[2]*r.w; a1 += c[2]*r.z; a2 += c[2]*r.y; a3 += c[2]*r.x; }
            { const float4 r = gload(COMP[4][h], ti,  rcg);  // g4: elem 3-q
              a0 += c[4]*r.w; a1 += c[4]*r.z; a2 += c[4]*r.y; a3 += c[4]*r.x; }
            { const float4 r = gload(COMP[6][h], rti, cg);   // g6: elem q
              a0 += c[6]*r.x; a1 += c[6]*r.y; a2 += c[6]*r.z; a3 += c[6]*r.w; }
            // transpose groups from LDS (2-way max bank alias = free)
            float t[4];
            #pragma unroll
            for (int q = 0; q < 4; ++q) {
                const int tj = cg + q, rtj = TS - 1 - tj;
                t[q] = c[1] * lds[COMP[1][h]][tj  * PITCH + rti]
                     + c[3] * lds[COMP[3][h]][rtj * PITCH + ti ]
                     + c[5] * lds[COMP[5][h]][tj  * PITCH + ti ]
                     + c[7] * lds[COMP[7][h]][rtj * PITCH + rti];
            }
            const int TIh = tile_i(h, I, J, rI, rJ);
            const int TJh = tile_j(h, I, J, rI, rJ);
            *reinterpret_cast<float4*>(
                oplane + (size_t)(TIh * TS + ti) * N + TJh * TS + cg)
                = make_float4(a0 + t[0], a1 + t[1], a2 + t[2], a3 + t[3]);
        }
    } else {
        // ------------- degenerate orbits: <=4 output tiles -------------
        const int cls = (o < 6) ? 1 : (o < 9) ? 2 : 3;
        const int nh  = (cls == 3) ? 1 : 4;
        #pragma unroll
        for (int h = 0; h < 4; ++h) {
            if (h < nh) {               // block-uniform guard
                float a0 = 0.f, a1 = 0.f, a2 = 0.f, a3 = 0.f;
                { const float4 r = gload(COMP[0][h], ti,  cg);
                  a0 += c[0]*r.x; a1 += c[0]*r.y; a2 += c[0]*r.z; a3 += c[0]*r.w; }
                { const float4 r = gload(COMP[2][h], rti, rcg);
                  a0 += c[2]*r.w; a1 += c[2]*r.z; a2 += c[2]*r.y; a3 += c[2]*r.x; }
                { const float4 r = gload(COMP[4][h], ti,  rcg);
                  a0 += c[4]*r.w; a1 += c[4]*r.z; a2 += c[4]*r.y; a3 += c[4]*r.x; }
                { const float4 r = gload(COMP[6][h], rti, cg);
                  a0 += c[6]*r.x; a1 += c[6]*r.y; a2 += c[6]*r.z; a3 += c[6]*r.w; }
                // LDS slots: compile-time candidates, block-uniform select
                const int s1 = (cls==1) ? CAN1[COMP[1][h]] : (cls==2) ? CAN2[COMP[1][h]] : 0;
                const int s3 = (cls==1) ? CAN1[COMP[3][h]] : (cls==2) ? CAN2[COMP[3][h]] : 0;
                const int s5 = (cls==1) ? CAN1[COMP[5][h]] : (cls==2) ? CAN2[COMP[5][h]] : 0;
                const int s7 = (cls==1) ? CAN1[COMP[7][h]] : (cls==2) ? CAN2[COMP[7][h]] : 0;
                float t[4];
                #pragma unroll
                for (int q = 0; q < 4; ++q) {
                    const int tj = cg + q, rtj = TS - 1 - tj;
                    t[q] = c[1] * lds[s1][tj  * PITCH + rti]
                         + c[3] * lds[s3][rtj * PITCH + ti ]
                         + c[5] * lds[s5][tj  * PITCH + ti ]
                         + c[7] * lds[s7][rtj * PITCH + rti];
                }
                const int TIh = tile_i(h, I, J, rI, rJ);
                const int TJh = tile_j(h, I, J, rI, rJ);
                *reinterpret_cast<float4*>(
                    oplane + (size_t)(TIh * TS + ti) * N + TJh * TS + cg)
                    = make_float4(a0 + t[0], a1 + t[1], a2 + t[2], a3 + t[3]);
            }
        }
    }
}

extern "C" void kernel_launch(void* const* d_in, const int* in_sizes, int n_in,
                              void* d_out, int out_size, void* d_ws, size_t ws_size,
                              hipStream_t stream) {
    const float* x     = (const float*)d_in[0];
    const float* theta = (const float*)d_in[1];
    float* out = (float*)d_out;

    const int planes = in_sizes[0] / (N * N);   // 16*192 = 3072
    popmi_kernel<<<planes * 10, 256, 0, stream>>>(x, theta, out);
}